// Round 6
// baseline (143.881 us; speedup 1.0000x reference)
//
#include <hip/hip_runtime.h>

typedef _Float16 f16x8 __attribute__((ext_vector_type(8)));
typedef __fp16 fp16x2 __attribute__((ext_vector_type(2)));
typedef float f32x4 __attribute__((ext_vector_type(4)));

#define NTHR 256
constexpr float EPS = 1e-5f;
constexpr int NBLOCKS = 4096;   // 1048576 / 256 rows per block

// ---- ws byte offsets (written by prep_kernel every call) ----
#define TAB_B   0       // f16 [29][8]  embedding-MLP table (464 B used)
#define W1_B    1024    // f16 [48][64]  fc1 (bn1+cbn folded), out-major, k padded
#define W2_B    7168    // f16 [32][64]  fc2 (bn2 folded)
#define W3_B    11264   // f16 [16][32]  fc3 (bn3 folded)
#define B1_B    12288   // f32 [48]
#define B2_B    12544   // f32 [32]
#define B3_B    12672   // f32 [16]
#define W4_B    12736   // f32 [16]  (fc4 row1-row0, padded)
#define B4_B    12800   // f32 [1]

__device__ __forceinline__ ushort f16bits(float x) {
    union { _Float16 h; ushort u; } c; c.h = (_Float16)x; return c.u;
}
__device__ __forceinline__ uint pk2(float a, float b) {
    union { fp16x2 h; uint u; } c; c.h = __builtin_amdgcn_cvt_pkrtz(a, b); return c.u;
}
__device__ __forceinline__ uint pkrelu(float a, float b) {
    return pk2(fmaxf(a, 0.f), fmaxf(b, 0.f));
}
__device__ __forceinline__ f16x8 mk8(uint a, uint b, uint c, uint d) {
    union { uint u[4]; f16x8 v; } f;
    f.u[0] = a; f.u[1] = b; f.u[2] = c; f.u[3] = d;
    return f.v;
}

// Weight A-fragment from global [n][stride] f16: lane m=l&15, k = kb+4g.., kb+16+4g..
__device__ __forceinline__ f16x8 ldw_frag(const ushort* wp, int m, int stride, int kb, int g) {
    const ushort* p = wp + m * stride + kb + 4 * g;
    uint2 lo = *(const uint2*)p;
    uint2 hi = *(const uint2*)(p + 16);
    return mk8(lo.x, lo.y, hi.x, hi.y);
}

__global__ __launch_bounds__(NTHR) void prep_kernel(
    const float* __restrict__ embt, const float* __restrict__ w1,
    const float* __restrict__ b1,   const float* __restrict__ w2,
    const float* __restrict__ b2,
    const float* __restrict__ cbn_g, const float* __restrict__ cbn_b,
    const float* __restrict__ cbn_m, const float* __restrict__ cbn_v,
    const float* __restrict__ f1w, const float* __restrict__ f1b,
    const float* __restrict__ f2w, const float* __restrict__ f2b,
    const float* __restrict__ f3w, const float* __restrict__ f3b,
    const float* __restrict__ f4w, const float* __restrict__ f4b,
    const float* __restrict__ bn1g, const float* __restrict__ bn1b,
    const float* __restrict__ bn1m, const float* __restrict__ bn1v,
    const float* __restrict__ bn2g, const float* __restrict__ bn2b,
    const float* __restrict__ bn2m, const float* __restrict__ bn2v,
    const float* __restrict__ bn3g, const float* __restrict__ bn3b,
    const float* __restrict__ bn3m, const float* __restrict__ bn3v,
    char* __restrict__ ws)
{
    const int t = threadIdx.x;
    ushort* tab = (ushort*)(ws + TAB_B);
    ushort* w1o = (ushort*)(ws + W1_B);
    ushort* w2o = (ushort*)(ws + W2_B);
    ushort* w3o = (ushort*)(ws + W3_B);
    float* b1o = (float*)(ws + B1_B);
    float* b2o = (float*)(ws + B2_B);
    float* b3o = (float*)(ws + B3_B);
    float* w4o = (float*)(ws + W4_B);
    float* b4o = (float*)(ws + B4_B);

    // embedding-MLP lookup table [29][8] f16 (cols 5-7 zero)
    for (int i = t; i < 232; i += NTHR) {
        int j = i / 8, c = i % 8;
        float xe = 0.f;
        if (c < 5) {
            xe = b2[j];
            for (int e = 0; e < 6; e++) {
                float a = b1[j * 6 + e];
                for (int d = 0; d < 6; d++)
                    a += embt[(j * 5 + c) * 6 + d] * w1[j * 36 + d * 6 + e];
                xe += fmaxf(a, 0.f) * w2[j * 6 + e];
            }
        }
        tab[i] = f16bits(xe);
    }
    // fc1: [48 out][64 k] f16, bn1 scale on rows, cbn scale on cols<7, pads zero
    for (int i = t; i < 3072; i += NTHR) {
        int n = i / 64, k = i % 64;
        float v = 0.f;
        if (n < 36 && k < 36) {
            float s1 = bn1g[n] * rsqrtf(bn1v[n] + EPS);
            v = f1w[n * 36 + k] * s1;
            if (k < 7) v *= cbn_g[k] * rsqrtf(cbn_v[k] + EPS);
        }
        w1o[i] = f16bits(v);
    }
    if (t < 48) {
        float v = 0.f;
        if (t < 36) {
            float s1 = bn1g[t] * rsqrtf(bn1v[t] + EPS);
            v = f1b[t] * s1 + bn1b[t] - bn1m[t] * s1;
            for (int k = 0; k < 7; k++) {
                float cs = cbn_g[k] * rsqrtf(cbn_v[k] + EPS);
                float ct = cbn_b[k] - cbn_m[k] * cs;
                v += f1w[t * 36 + k] * s1 * ct;
            }
        }
        b1o[t] = v;
    }
    // fc2: [32 out][64 k]
    for (int i = t; i < 2048; i += NTHR) {
        int n = i / 64, k = i % 64;
        float v = 0.f;
        if (n < 18 && k < 36) {
            float s = bn2g[n] * rsqrtf(bn2v[n] + EPS);
            v = f2w[n * 36 + k] * s;
        }
        w2o[i] = f16bits(v);
    }
    if (t < 32) {
        float v = 0.f;
        if (t < 18) {
            float s = bn2g[t] * rsqrtf(bn2v[t] + EPS);
            v = f2b[t] * s + bn2b[t] - bn2m[t] * s;
        }
        b2o[t] = v;
    }
    // fc3: [16 out][32 k]
    for (int i = t; i < 512; i += NTHR) {
        int n = i / 32, k = i % 32;
        float v = 0.f;
        if (n < 9 && k < 18) {
            float s = bn3g[n] * rsqrtf(bn3v[n] + EPS);
            v = f3w[n * 18 + k] * s;
        }
        w3o[i] = f16bits(v);
    }
    if (t < 16) {
        float v = 0.f;
        if (t < 9) {
            float s = bn3g[t] * rsqrtf(bn3v[t] + EPS);
            v = f3b[t] * s + bn3b[t] - bn3m[t] * s;
        }
        b3o[t] = v;
    }
    if (t < 16) w4o[t] = (t < 9) ? (f4w[9 + t] - f4w[t]) : 0.f;
    if (t == 0) b4o[0] = f4b[1] - f4b[0];
}

// X^T LDS layout: [256 rows][36 f16], 72 B row stride (no padding needed; b64-aligned)
#define XSTRIDE 72

__global__ __launch_bounds__(NTHR, 8) void recovery_net_kernel(
    const float* __restrict__ xcon, const int* __restrict__ xcat,
    const char* __restrict__ ws, float2* __restrict__ out)
{
    __shared__ __align__(16) char s_x[256 * XSTRIDE];   // 18432 B — ONLY LDS

    const int t = threadIdx.x;
    const int lane = t & 63, w = t >> 6;
    const int l15 = lane & 15, g = lane >> 4;
    const ushort* tabh = (const ushort*)(ws + TAB_B);

    // ---- fused stage + gather + scatter into X^T (f16) ----
    // xcon: 448 float4 over [256][7] f32
    {
        const float4* src = (const float4*)(xcon + (size_t)blockIdx.x * 1792);
        for (int idx = t; idx < 448; idx += NTHR) {
            float4 v = src[idx];
            int i0 = idx * 4;
#pragma unroll
            for (int e = 0; e < 4; e++) {
                int i = i0 + e;
                unsigned r = (unsigned)i / 7u;
                unsigned k = (unsigned)i - r * 7u;
                float f = (e == 0) ? v.x : (e == 1) ? v.y : (e == 2) ? v.z : v.w;
                *(ushort*)(s_x + r * XSTRIDE + 2 * k) = f16bits(f);
            }
        }
    }
    // xcat: 1856 int4 over [256][29] i32; lookup table inline (tab is L1-resident)
    {
        const int4* src = (const int4*)(xcat + (size_t)blockIdx.x * 7424);
        for (int idx = t; idx < 1856; idx += NTHR) {
            int4 v = src[idx];
            int i0 = idx * 4;
#pragma unroll
            for (int e = 0; e < 4; e++) {
                int i = i0 + e;
                unsigned r = (unsigned)i / 29u;
                unsigned j = (unsigned)i - r * 29u;
                int c = (e == 0) ? v.x : (e == 1) ? v.y : (e == 2) ? v.z : v.w;
                ushort h = tabh[j * 8 + c];
                *(ushort*)(s_x + r * XSTRIDE + 14 + 2 * j) = h;
            }
        }
    }
    __syncthreads();

    const int rb = w * 64;  // this wave's row strip
    const ushort* w1p = (const ushort*)(ws + W1_B);
    const ushort* w2p = (const ushort*)(ws + W2_B);
    const ushort* w3p = (const ushort*)(ws + W3_B);
    const float* b1p = (const float*)(ws + B1_B);
    const float* b2p = (const float*)(ws + B2_B);
    const float* b3p = (const float*)(ws + B3_B);
    const float* w4p = (const float*)(ws + W4_B);
    const float* b4p = (const float*)(ws + B4_B);

    // ---- weight A-fragments (features = m), held across tiles ----
    f16x8 a1[3][2], a2[2][2], a3;
#pragma unroll
    for (int mt = 0; mt < 3; mt++) {
        a1[mt][0] = ldw_frag(w1p, mt * 16 + l15, 64, 0, g);
        a1[mt][1] = ldw_frag(w1p, mt * 16 + l15, 64, 32, g);
    }
#pragma unroll
    for (int mt = 0; mt < 2; mt++) {
        a2[mt][0] = ldw_frag(w2p, mt * 16 + l15, 64, 0, g);
        a2[mt][1] = ldw_frag(w2p, mt * 16 + l15, 64, 32, g);
    }
    a3 = ldw_frag(w3p, l15, 32, 0, g);

    // biases / fc4 (per-lane float4 at row m = mt*16 + 4g + r)
    const float4 b1v0 = *(const float4*)(b1p + 4 * g);
    const float4 b1v1 = *(const float4*)(b1p + 16 + 4 * g);
    const float4 b1v2 = *(const float4*)(b1p + 32 + 4 * g);
    const float4 b2v0 = *(const float4*)(b2p + 4 * g);
    const float4 b2v1 = *(const float4*)(b2p + 16 + 4 * g);
    const float4 b3v  = *(const float4*)(b3p + 4 * g);
    const float4 w4v  = *(const float4*)(w4p + 4 * g);
    const float b4s = *b4p;

    // ---- 4 batch tiles of 16 rows; whole chain in registers ----
#pragma unroll
    for (int bt = 0; bt < 4; bt++) {
        const char* xr = s_x + (rb + 16 * bt + l15) * XSTRIDE;
        uint2 q0 = *(const uint2*)(xr + 8 * g);        // features 4g..4g+3
        uint2 q1 = *(const uint2*)(xr + 32 + 8 * g);   // features 16+4g..19+4g
        uint2 q2 = *(const uint2*)(xr + 64);           // features 32..35
        f16x8 xb0 = mk8(q0.x, q0.y, q1.x, q1.y);
        f16x8 xb1 = mk8(g == 0 ? q2.x : 0u, g == 0 ? q2.y : 0u, 0u, 0u);

        // fc1: h1^T tiles (features 0..47)
        f32x4 c10 = f32x4{b1v0.x, b1v0.y, b1v0.z, b1v0.w};
        f32x4 c11 = f32x4{b1v1.x, b1v1.y, b1v1.z, b1v1.w};
        f32x4 c12 = f32x4{b1v2.x, b1v2.y, b1v2.z, b1v2.w};
        c10 = __builtin_amdgcn_mfma_f32_16x16x32_f16(a1[0][0], xb0, c10, 0, 0, 0);
        c11 = __builtin_amdgcn_mfma_f32_16x16x32_f16(a1[1][0], xb0, c11, 0, 0, 0);
        c12 = __builtin_amdgcn_mfma_f32_16x16x32_f16(a1[2][0], xb0, c12, 0, 0, 0);
        c10 = __builtin_amdgcn_mfma_f32_16x16x32_f16(a1[0][1], xb1, c10, 0, 0, 0);
        c11 = __builtin_amdgcn_mfma_f32_16x16x32_f16(a1[1][1], xb1, c11, 0, 0, 0);
        c12 = __builtin_amdgcn_mfma_f32_16x16x32_f16(a1[2][1], xb1, c12, 0, 0, 0);

        // relu + pack: C1 tiles are exactly fc2's B-fragments
        f16x8 h0 = mk8(pkrelu(c10.x, c10.y), pkrelu(c10.z, c10.w),
                       pkrelu(c11.x, c11.y), pkrelu(c11.z, c11.w));
        f16x8 h1 = mk8(pkrelu(c12.x, c12.y), pkrelu(c12.z, c12.w), 0u, 0u);

        // fc2
        f32x4 c20 = f32x4{b2v0.x, b2v0.y, b2v0.z, b2v0.w};
        f32x4 c21 = f32x4{b2v1.x, b2v1.y, b2v1.z, b2v1.w};
        c20 = __builtin_amdgcn_mfma_f32_16x16x32_f16(a2[0][0], h0, c20, 0, 0, 0);
        c21 = __builtin_amdgcn_mfma_f32_16x16x32_f16(a2[1][0], h0, c21, 0, 0, 0);
        c20 = __builtin_amdgcn_mfma_f32_16x16x32_f16(a2[0][1], h1, c20, 0, 0, 0);
        c21 = __builtin_amdgcn_mfma_f32_16x16x32_f16(a2[1][1], h1, c21, 0, 0, 0);

        // fc3
        f16x8 h2 = mk8(pkrelu(c20.x, c20.y), pkrelu(c20.z, c20.w),
                       pkrelu(c21.x, c21.y), pkrelu(c21.z, c21.w));
        f32x4 c3 = f32x4{b3v.x, b3v.y, b3v.z, b3v.w};
        c3 = __builtin_amdgcn_mfma_f32_16x16x32_f16(a3, h2, c3, 0, 0, 0);

        // fc4 delta + sigmoid: reduce feature partials across g-groups
        float part = fmaxf(c3.x, 0.f) * w4v.x + fmaxf(c3.y, 0.f) * w4v.y +
                     fmaxf(c3.z, 0.f) * w4v.z + fmaxf(c3.w, 0.f) * w4v.w;
        part += __shfl_xor(part, 16);
        part += __shfl_xor(part, 32);
        float d = part + b4s;
        float p1 = 1.f / (1.f + __expf(-d));
        if (g == 0)
            out[blockIdx.x * 256 + rb + 16 * bt + l15] = make_float2(1.f - p1, p1);
    }
}

extern "C" void kernel_launch(void* const* d_in, const int* in_sizes, int n_in,
                              void* d_out, int out_size, void* d_ws, size_t ws_size,
                              hipStream_t stream) {
    (void)in_sizes; (void)n_in; (void)ws_size; (void)out_size;
    char* ws = (char*)d_ws;
    prep_kernel<<<1, NTHR, 0, stream>>>(
        (const float*)d_in[2],  (const float*)d_in[3],
        (const float*)d_in[4],  (const float*)d_in[5],
        (const float*)d_in[6],
        (const float*)d_in[7],  (const float*)d_in[8],
        (const float*)d_in[9],  (const float*)d_in[10],
        (const float*)d_in[11], (const float*)d_in[12],
        (const float*)d_in[13], (const float*)d_in[14],
        (const float*)d_in[15], (const float*)d_in[16],
        (const float*)d_in[17], (const float*)d_in[18],
        (const float*)d_in[19], (const float*)d_in[20],
        (const float*)d_in[21], (const float*)d_in[22],
        (const float*)d_in[23], (const float*)d_in[24],
        (const float*)d_in[25], (const float*)d_in[26],
        (const float*)d_in[27], (const float*)d_in[28],
        (const float*)d_in[29], (const float*)d_in[30],
        ws);
    recovery_net_kernel<<<NBLOCKS, NTHR, 0, stream>>>(
        (const float*)d_in[0], (const int*)d_in[1], ws, (float2*)d_out);
}

// Round 7
// 117.322 us; speedup vs baseline: 1.2264x; 1.2264x over previous
//
#include <hip/hip_runtime.h>

typedef _Float16 f16x8 __attribute__((ext_vector_type(8)));
typedef __fp16 fp16x2 __attribute__((ext_vector_type(2)));
typedef float f32x4 __attribute__((ext_vector_type(4)));

#define NTHR 256
constexpr float EPS = 1e-5f;
constexpr int NBLOCKS = 4096;   // 1048576 / 256 rows per block

// ---- ws byte offsets (written by prep_kernel every call) ----
#define TAB_B   0       // f16 [29][8]  embedding-MLP table (464 B used)
#define W1_B    1024    // f16 [48][64]  fc1 (bn1+cbn folded), out-major, k padded
#define W2_B    7168    // f16 [32][64]  fc2 (bn2 folded)
#define W3_B    11264   // f16 [16][32]  fc3 (bn3 folded)
#define B1_B    12288   // f32 [48]
#define B2_B    12544   // f32 [32]
#define B3_B    12672   // f32 [16]
#define W4_B    12736   // f32 [16]  (fc4 row1-row0, padded)
#define B4_B    12800   // f32 [1]

__device__ __forceinline__ ushort f16bits(float x) {
    union { _Float16 h; ushort u; } c; c.h = (_Float16)x; return c.u;
}
__device__ __forceinline__ uint pk2(float a, float b) {
    union { fp16x2 h; uint u; } c; c.h = __builtin_amdgcn_cvt_pkrtz(a, b); return c.u;
}
__device__ __forceinline__ uint pkrelu(float a, float b) {
    return pk2(fmaxf(a, 0.f), fmaxf(b, 0.f));
}
__device__ __forceinline__ f16x8 mk8(uint a, uint b, uint c, uint d) {
    union { uint u[4]; f16x8 v; } f;
    f.u[0] = a; f.u[1] = b; f.u[2] = c; f.u[3] = d;
    return f.v;
}

// Weight A-fragment from global [n][stride] f16: lane m=l&15, k = kb+4g.., kb+16+4g..
__device__ __forceinline__ f16x8 ldw_frag(const ushort* wp, int m, int stride, int kb, int g) {
    const ushort* p = wp + m * stride + kb + 4 * g;
    uint2 lo = *(const uint2*)p;
    uint2 hi = *(const uint2*)(p + 16);
    return mk8(lo.x, lo.y, hi.x, hi.y);
}

__global__ __launch_bounds__(NTHR) void prep_kernel(
    const float* __restrict__ embt, const float* __restrict__ w1,
    const float* __restrict__ b1,   const float* __restrict__ w2,
    const float* __restrict__ b2,
    const float* __restrict__ cbn_g, const float* __restrict__ cbn_b,
    const float* __restrict__ cbn_m, const float* __restrict__ cbn_v,
    const float* __restrict__ f1w, const float* __restrict__ f1b,
    const float* __restrict__ f2w, const float* __restrict__ f2b,
    const float* __restrict__ f3w, const float* __restrict__ f3b,
    const float* __restrict__ f4w, const float* __restrict__ f4b,
    const float* __restrict__ bn1g, const float* __restrict__ bn1b,
    const float* __restrict__ bn1m, const float* __restrict__ bn1v,
    const float* __restrict__ bn2g, const float* __restrict__ bn2b,
    const float* __restrict__ bn2m, const float* __restrict__ bn2v,
    const float* __restrict__ bn3g, const float* __restrict__ bn3b,
    const float* __restrict__ bn3m, const float* __restrict__ bn3v,
    char* __restrict__ ws)
{
    const int t = threadIdx.x;
    ushort* tab = (ushort*)(ws + TAB_B);
    ushort* w1o = (ushort*)(ws + W1_B);
    ushort* w2o = (ushort*)(ws + W2_B);
    ushort* w3o = (ushort*)(ws + W3_B);
    float* b1o = (float*)(ws + B1_B);
    float* b2o = (float*)(ws + B2_B);
    float* b3o = (float*)(ws + B3_B);
    float* w4o = (float*)(ws + W4_B);
    float* b4o = (float*)(ws + B4_B);

    // embedding-MLP lookup table [29][8] f16 (cols 5-7 zero)
    for (int i = t; i < 232; i += NTHR) {
        int j = i / 8, c = i % 8;
        float xe = 0.f;
        if (c < 5) {
            xe = b2[j];
            for (int e = 0; e < 6; e++) {
                float a = b1[j * 6 + e];
                for (int d = 0; d < 6; d++)
                    a += embt[(j * 5 + c) * 6 + d] * w1[j * 36 + d * 6 + e];
                xe += fmaxf(a, 0.f) * w2[j * 6 + e];
            }
        }
        tab[i] = f16bits(xe);
    }
    // fc1: [48 out][64 k] f16, bn1 scale on rows, cbn scale on cols<7, pads zero
    for (int i = t; i < 3072; i += NTHR) {
        int n = i / 64, k = i % 64;
        float v = 0.f;
        if (n < 36 && k < 36) {
            float s1 = bn1g[n] * rsqrtf(bn1v[n] + EPS);
            v = f1w[n * 36 + k] * s1;
            if (k < 7) v *= cbn_g[k] * rsqrtf(cbn_v[k] + EPS);
        }
        w1o[i] = f16bits(v);
    }
    if (t < 48) {
        float v = 0.f;
        if (t < 36) {
            float s1 = bn1g[t] * rsqrtf(bn1v[t] + EPS);
            v = f1b[t] * s1 + bn1b[t] - bn1m[t] * s1;
            for (int k = 0; k < 7; k++) {
                float cs = cbn_g[k] * rsqrtf(cbn_v[k] + EPS);
                float ct = cbn_b[k] - cbn_m[k] * cs;
                v += f1w[t * 36 + k] * s1 * ct;
            }
        }
        b1o[t] = v;
    }
    // fc2: [32 out][64 k]
    for (int i = t; i < 2048; i += NTHR) {
        int n = i / 64, k = i % 64;
        float v = 0.f;
        if (n < 18 && k < 36) {
            float s = bn2g[n] * rsqrtf(bn2v[n] + EPS);
            v = f2w[n * 36 + k] * s;
        }
        w2o[i] = f16bits(v);
    }
    if (t < 32) {
        float v = 0.f;
        if (t < 18) {
            float s = bn2g[t] * rsqrtf(bn2v[t] + EPS);
            v = f2b[t] * s + bn2b[t] - bn2m[t] * s;
        }
        b2o[t] = v;
    }
    // fc3: [16 out][32 k]
    for (int i = t; i < 512; i += NTHR) {
        int n = i / 32, k = i % 32;
        float v = 0.f;
        if (n < 9 && k < 18) {
            float s = bn3g[n] * rsqrtf(bn3v[n] + EPS);
            v = f3w[n * 18 + k] * s;
        }
        w3o[i] = f16bits(v);
    }
    if (t < 16) {
        float v = 0.f;
        if (t < 9) {
            float s = bn3g[t] * rsqrtf(bn3v[t] + EPS);
            v = f3b[t] * s + bn3b[t] - bn3m[t] * s;
        }
        b3o[t] = v;
    }
    if (t < 16) w4o[t] = (t < 9) ? (f4w[9 + t] - f4w[t]) : 0.f;
    if (t == 0) b4o[0] = f4b[1] - f4b[0];
}

// X^T LDS layout: [256 rows][36 f16], 72 B row stride (b64-aligned)
#define XSTRIDE 72

__global__ __launch_bounds__(NTHR, 6) void recovery_net_kernel(
    const float* __restrict__ xcon, const int* __restrict__ xcat,
    const char* __restrict__ ws, float2* __restrict__ out)
{
    __shared__ __align__(16) char s_x[256 * XSTRIDE];   // 18432 B — ONLY LDS

    const int t = threadIdx.x;
    const int lane = t & 63, w = t >> 6;
    const int l15 = lane & 15, g = lane >> 4;
    const ushort* tabh = (const ushort*)(ws + TAB_B);

    // ---- fused stage + gather + scatter into X^T (f16) ----
    // xcon: 448 float4 over [256][7] f32
    {
        const float4* src = (const float4*)(xcon + (size_t)blockIdx.x * 1792);
        for (int idx = t; idx < 448; idx += NTHR) {
            float4 v = src[idx];
            int i0 = idx * 4;
#pragma unroll
            for (int e = 0; e < 4; e++) {
                int i = i0 + e;
                unsigned r = (unsigned)i / 7u;
                unsigned k = (unsigned)i - r * 7u;
                float f = (e == 0) ? v.x : (e == 1) ? v.y : (e == 2) ? v.z : v.w;
                *(ushort*)(s_x + r * XSTRIDE + 2 * k) = f16bits(f);
            }
        }
    }
    // xcat: 1856 int4 over [256][29] i32; lookup table inline (tab is L1-resident)
    {
        const int4* src = (const int4*)(xcat + (size_t)blockIdx.x * 7424);
        for (int idx = t; idx < 1856; idx += NTHR) {
            int4 v = src[idx];
            int i0 = idx * 4;
#pragma unroll
            for (int e = 0; e < 4; e++) {
                int i = i0 + e;
                unsigned r = (unsigned)i / 29u;
                unsigned j = (unsigned)i - r * 29u;
                int c = (e == 0) ? v.x : (e == 1) ? v.y : (e == 2) ? v.z : v.w;
                ushort h = tabh[j * 8 + c];
                *(ushort*)(s_x + r * XSTRIDE + 14 + 2 * j) = h;
            }
        }
    }
    __syncthreads();

    const int rb = w * 64;  // this wave's row strip
    const ushort* w1p = (const ushort*)(ws + W1_B);
    const ushort* w2p = (const ushort*)(ws + W2_B);
    const ushort* w3p = (const ushort*)(ws + W3_B);
    const float* b1p = (const float*)(ws + B1_B);
    const float* b2p = (const float*)(ws + B2_B);
    const float* b3p = (const float*)(ws + B3_B);
    const float* w4p = (const float*)(ws + W4_B);
    const float* b4p = (const float*)(ws + B4_B);

    // ---- weight A-fragments (features = m), held across tiles ----
    f16x8 a1[3][2], a2[2][2], a3;
#pragma unroll
    for (int mt = 0; mt < 3; mt++) {
        a1[mt][0] = ldw_frag(w1p, mt * 16 + l15, 64, 0, g);
        a1[mt][1] = ldw_frag(w1p, mt * 16 + l15, 64, 32, g);
    }
#pragma unroll
    for (int mt = 0; mt < 2; mt++) {
        a2[mt][0] = ldw_frag(w2p, mt * 16 + l15, 64, 0, g);
        a2[mt][1] = ldw_frag(w2p, mt * 16 + l15, 64, 32, g);
    }
    a3 = ldw_frag(w3p, l15, 32, 0, g);

    // biases / fc4 (per-lane float4 at row m = mt*16 + 4g + r)
    const float4 b1v0 = *(const float4*)(b1p + 4 * g);
    const float4 b1v1 = *(const float4*)(b1p + 16 + 4 * g);
    const float4 b1v2 = *(const float4*)(b1p + 32 + 4 * g);
    const float4 b2v0 = *(const float4*)(b2p + 4 * g);
    const float4 b2v1 = *(const float4*)(b2p + 16 + 4 * g);
    const float4 b3v  = *(const float4*)(b3p + 4 * g);
    const float4 w4v  = *(const float4*)(w4p + 4 * g);
    const float b4s = *b4p;

    // ---- 4 batch tiles of 16 rows; whole chain in registers ----
#pragma unroll
    for (int bt = 0; bt < 4; bt++) {
        const char* xr = s_x + (rb + 16 * bt + l15) * XSTRIDE;
        uint2 q0 = *(const uint2*)(xr + 8 * g);        // features 4g..4g+3
        uint2 q1 = *(const uint2*)(xr + 32 + 8 * g);   // features 16+4g..19+4g
        uint2 q2 = *(const uint2*)(xr + 64);           // features 32..35
        f16x8 xb0 = mk8(q0.x, q0.y, q1.x, q1.y);
        f16x8 xb1 = mk8(g == 0 ? q2.x : 0u, g == 0 ? q2.y : 0u, 0u, 0u);

        // fc1: h1^T tiles (features 0..47)
        f32x4 c10 = f32x4{b1v0.x, b1v0.y, b1v0.z, b1v0.w};
        f32x4 c11 = f32x4{b1v1.x, b1v1.y, b1v1.z, b1v1.w};
        f32x4 c12 = f32x4{b1v2.x, b1v2.y, b1v2.z, b1v2.w};
        c10 = __builtin_amdgcn_mfma_f32_16x16x32_f16(a1[0][0], xb0, c10, 0, 0, 0);
        c11 = __builtin_amdgcn_mfma_f32_16x16x32_f16(a1[1][0], xb0, c11, 0, 0, 0);
        c12 = __builtin_amdgcn_mfma_f32_16x16x32_f16(a1[2][0], xb0, c12, 0, 0, 0);
        c10 = __builtin_amdgcn_mfma_f32_16x16x32_f16(a1[0][1], xb1, c10, 0, 0, 0);
        c11 = __builtin_amdgcn_mfma_f32_16x16x32_f16(a1[1][1], xb1, c11, 0, 0, 0);
        c12 = __builtin_amdgcn_mfma_f32_16x16x32_f16(a1[2][1], xb1, c12, 0, 0, 0);

        // relu + pack: C1 tiles are exactly fc2's B-fragments
        f16x8 h0 = mk8(pkrelu(c10.x, c10.y), pkrelu(c10.z, c10.w),
                       pkrelu(c11.x, c11.y), pkrelu(c11.z, c11.w));
        f16x8 h1 = mk8(pkrelu(c12.x, c12.y), pkrelu(c12.z, c12.w), 0u, 0u);

        // fc2
        f32x4 c20 = f32x4{b2v0.x, b2v0.y, b2v0.z, b2v0.w};
        f32x4 c21 = f32x4{b2v1.x, b2v1.y, b2v1.z, b2v1.w};
        c20 = __builtin_amdgcn_mfma_f32_16x16x32_f16(a2[0][0], h0, c20, 0, 0, 0);
        c21 = __builtin_amdgcn_mfma_f32_16x16x32_f16(a2[1][0], h0, c21, 0, 0, 0);
        c20 = __builtin_amdgcn_mfma_f32_16x16x32_f16(a2[0][1], h1, c20, 0, 0, 0);
        c21 = __builtin_amdgcn_mfma_f32_16x16x32_f16(a2[1][1], h1, c21, 0, 0, 0);

        // fc3
        f16x8 h2 = mk8(pkrelu(c20.x, c20.y), pkrelu(c20.z, c20.w),
                       pkrelu(c21.x, c21.y), pkrelu(c21.z, c21.w));
        f32x4 c3 = f32x4{b3v.x, b3v.y, b3v.z, b3v.w};
        c3 = __builtin_amdgcn_mfma_f32_16x16x32_f16(a3, h2, c3, 0, 0, 0);

        // fc4 delta + sigmoid: reduce feature partials across g-groups
        float part = fmaxf(c3.x, 0.f) * w4v.x + fmaxf(c3.y, 0.f) * w4v.y +
                     fmaxf(c3.z, 0.f) * w4v.z + fmaxf(c3.w, 0.f) * w4v.w;
        part += __shfl_xor(part, 16);
        part += __shfl_xor(part, 32);
        float d = part + b4s;
        float p1 = 1.f / (1.f + __expf(-d));
        if (g == 0)
            out[blockIdx.x * 256 + rb + 16 * bt + l15] = make_float2(1.f - p1, p1);
    }
}

extern "C" void kernel_launch(void* const* d_in, const int* in_sizes, int n_in,
                              void* d_out, int out_size, void* d_ws, size_t ws_size,
                              hipStream_t stream) {
    (void)in_sizes; (void)n_in; (void)ws_size; (void)out_size;
    char* ws = (char*)d_ws;
    prep_kernel<<<1, NTHR, 0, stream>>>(
        (const float*)d_in[2],  (const float*)d_in[3],
        (const float*)d_in[4],  (const float*)d_in[5],
        (const float*)d_in[6],
        (const float*)d_in[7],  (const float*)d_in[8],
        (const float*)d_in[9],  (const float*)d_in[10],
        (const float*)d_in[11], (const float*)d_in[12],
        (const float*)d_in[13], (const float*)d_in[14],
        (const float*)d_in[15], (const float*)d_in[16],
        (const float*)d_in[17], (const float*)d_in[18],
        (const float*)d_in[19], (const float*)d_in[20],
        (const float*)d_in[21], (const float*)d_in[22],
        (const float*)d_in[23], (const float*)d_in[24],
        (const float*)d_in[25], (const float*)d_in[26],
        (const float*)d_in[27], (const float*)d_in[28],
        (const float*)d_in[29], (const float*)d_in[30],
        ws);
    recovery_net_kernel<<<NBLOCKS, NTHR, 0, stream>>>(
        (const float*)d_in[0], (const int*)d_in[1], ws, (float2*)d_out);
}

// Round 8
// 92.334 us; speedup vs baseline: 1.5583x; 1.2706x over previous
//
#include <hip/hip_runtime.h>

typedef _Float16 f16x8 __attribute__((ext_vector_type(8)));
typedef __fp16 fp16x2 __attribute__((ext_vector_type(2)));
typedef float f32x4 __attribute__((ext_vector_type(4)));

#define NTHR 256
constexpr float EPS = 1e-5f;
constexpr int NBLOCKS = 4096;   // 1048576 / 256 rows per block

// ---- ws byte offsets (written by prep_kernel every call) ----
#define TAB_B   0       // f16 [29][8]  embedding-MLP table (464 B used)
#define W1_B    1024    // f16 [48][64]  fc1 (bn1+cbn folded), out-major, k padded
#define W2_B    7168    // f16 [32][64]  fc2 (bn2 folded)
#define W3_B    11264   // f16 [16][32]  fc3 (bn3 folded)
#define B1_B    12288   // f32 [48]
#define B2_B    12544   // f32 [32]
#define B3_B    12672   // f32 [16]
#define W4_B    12736   // f32 [16]  (fc4 row1-row0, padded)
#define B4_B    12800   // f32 [1]

__device__ __forceinline__ ushort f16bits(float x) {
    union { _Float16 h; ushort u; } c; c.h = (_Float16)x; return c.u;
}
__device__ __forceinline__ uint pk2(float a, float b) {
    union { fp16x2 h; uint u; } c; c.h = __builtin_amdgcn_cvt_pkrtz(a, b); return c.u;
}
__device__ __forceinline__ uint pkrelu(float a, float b) {
    return pk2(fmaxf(a, 0.f), fmaxf(b, 0.f));
}
__device__ __forceinline__ f16x8 mk8(uint a, uint b, uint c, uint d) {
    union { uint u[4]; f16x8 v; } f;
    f.u[0] = a; f.u[1] = b; f.u[2] = c; f.u[3] = d;
    return f.v;
}

// Weight A-fragment from global [n][stride] f16: lane m=l&15, k = kb+4g.., kb+16+4g..
__device__ __forceinline__ f16x8 ldw_frag(const ushort* wp, int m, int stride, int kb, int g) {
    const ushort* p = wp + m * stride + kb + 4 * g;
    uint2 lo = *(const uint2*)p;
    uint2 hi = *(const uint2*)(p + 16);
    return mk8(lo.x, lo.y, hi.x, hi.y);
}

__global__ __launch_bounds__(NTHR) void prep_kernel(
    const float* __restrict__ embt, const float* __restrict__ w1,
    const float* __restrict__ b1,   const float* __restrict__ w2,
    const float* __restrict__ b2,
    const float* __restrict__ cbn_g, const float* __restrict__ cbn_b,
    const float* __restrict__ cbn_m, const float* __restrict__ cbn_v,
    const float* __restrict__ f1w, const float* __restrict__ f1b,
    const float* __restrict__ f2w, const float* __restrict__ f2b,
    const float* __restrict__ f3w, const float* __restrict__ f3b,
    const float* __restrict__ f4w, const float* __restrict__ f4b,
    const float* __restrict__ bn1g, const float* __restrict__ bn1b,
    const float* __restrict__ bn1m, const float* __restrict__ bn1v,
    const float* __restrict__ bn2g, const float* __restrict__ bn2b,
    const float* __restrict__ bn2m, const float* __restrict__ bn2v,
    const float* __restrict__ bn3g, const float* __restrict__ bn3b,
    const float* __restrict__ bn3m, const float* __restrict__ bn3v,
    char* __restrict__ ws)
{
    const int t = threadIdx.x;
    ushort* tab = (ushort*)(ws + TAB_B);
    ushort* w1o = (ushort*)(ws + W1_B);
    ushort* w2o = (ushort*)(ws + W2_B);
    ushort* w3o = (ushort*)(ws + W3_B);
    float* b1o = (float*)(ws + B1_B);
    float* b2o = (float*)(ws + B2_B);
    float* b3o = (float*)(ws + B3_B);
    float* w4o = (float*)(ws + W4_B);
    float* b4o = (float*)(ws + B4_B);

    // embedding-MLP lookup table [29][8] f16 (cols 5-7 zero)
    for (int i = t; i < 232; i += NTHR) {
        int j = i / 8, c = i % 8;
        float xe = 0.f;
        if (c < 5) {
            xe = b2[j];
            for (int e = 0; e < 6; e++) {
                float a = b1[j * 6 + e];
                for (int d = 0; d < 6; d++)
                    a += embt[(j * 5 + c) * 6 + d] * w1[j * 36 + d * 6 + e];
                xe += fmaxf(a, 0.f) * w2[j * 6 + e];
            }
        }
        tab[i] = f16bits(xe);
    }
    // fc1: [48 out][64 k] f16, bn1 scale on rows, cbn scale on cols<7, pads zero
    for (int i = t; i < 3072; i += NTHR) {
        int n = i / 64, k = i % 64;
        float v = 0.f;
        if (n < 36 && k < 36) {
            float s1 = bn1g[n] * rsqrtf(bn1v[n] + EPS);
            v = f1w[n * 36 + k] * s1;
            if (k < 7) v *= cbn_g[k] * rsqrtf(cbn_v[k] + EPS);
        }
        w1o[i] = f16bits(v);
    }
    if (t < 48) {
        float v = 0.f;
        if (t < 36) {
            float s1 = bn1g[t] * rsqrtf(bn1v[t] + EPS);
            v = f1b[t] * s1 + bn1b[t] - bn1m[t] * s1;
            for (int k = 0; k < 7; k++) {
                float cs = cbn_g[k] * rsqrtf(cbn_v[k] + EPS);
                float ct = cbn_b[k] - cbn_m[k] * cs;
                v += f1w[t * 36 + k] * s1 * ct;
            }
        }
        b1o[t] = v;
    }
    // fc2: [32 out][64 k]
    for (int i = t; i < 2048; i += NTHR) {
        int n = i / 64, k = i % 64;
        float v = 0.f;
        if (n < 18 && k < 36) {
            float s = bn2g[n] * rsqrtf(bn2v[n] + EPS);
            v = f2w[n * 36 + k] * s;
        }
        w2o[i] = f16bits(v);
    }
    if (t < 32) {
        float v = 0.f;
        if (t < 18) {
            float s = bn2g[t] * rsqrtf(bn2v[t] + EPS);
            v = f2b[t] * s + bn2b[t] - bn2m[t] * s;
        }
        b2o[t] = v;
    }
    // fc3: [16 out][32 k]
    for (int i = t; i < 512; i += NTHR) {
        int n = i / 32, k = i % 32;
        float v = 0.f;
        if (n < 9 && k < 18) {
            float s = bn3g[n] * rsqrtf(bn3v[n] + EPS);
            v = f3w[n * 18 + k] * s;
        }
        w3o[i] = f16bits(v);
    }
    if (t < 16) {
        float v = 0.f;
        if (t < 9) {
            float s = bn3g[t] * rsqrtf(bn3v[t] + EPS);
            v = f3b[t] * s + bn3b[t] - bn3m[t] * s;
        }
        b3o[t] = v;
    }
    if (t < 16) w4o[t] = (t < 9) ? (f4w[9 + t] - f4w[t]) : 0.f;
    if (t == 0) b4o[0] = f4b[1] - f4b[0];
}

// X^T LDS layout: [256 rows][36 f16], 72 B row stride (b64-aligned)
#define XSTRIDE 72

__global__ __launch_bounds__(NTHR, 4) void recovery_net_kernel(
    const float* __restrict__ xcon, const int* __restrict__ xcat,
    const char* __restrict__ ws, float2* __restrict__ out)
{
    __shared__ __align__(16) char s_x[256 * XSTRIDE];   // 18432 B — ONLY LDS

    const int t = threadIdx.x;
    const int lane = t & 63, w = t >> 6;
    const int l15 = lane & 15, g = lane >> 4;
    const ushort* tabh = (const ushort*)(ws + TAB_B);

    // ---- fused stage + gather + scatter into X^T (f16) ----
    // xcon: 448 float4 over [256][7] f32
    {
        const float4* src = (const float4*)(xcon + (size_t)blockIdx.x * 1792);
        for (int idx = t; idx < 448; idx += NTHR) {
            float4 v = src[idx];
            int i0 = idx * 4;
#pragma unroll
            for (int e = 0; e < 4; e++) {
                int i = i0 + e;
                unsigned r = (unsigned)i / 7u;
                unsigned k = (unsigned)i - r * 7u;
                float f = (e == 0) ? v.x : (e == 1) ? v.y : (e == 2) ? v.z : v.w;
                *(ushort*)(s_x + r * XSTRIDE + 2 * k) = f16bits(f);
            }
        }
    }
    // xcat: 1856 int4 over [256][29] i32; lookup table inline (tab is L1-resident)
    {
        const int4* src = (const int4*)(xcat + (size_t)blockIdx.x * 7424);
        for (int idx = t; idx < 1856; idx += NTHR) {
            int4 v = src[idx];
            int i0 = idx * 4;
#pragma unroll
            for (int e = 0; e < 4; e++) {
                int i = i0 + e;
                unsigned r = (unsigned)i / 29u;
                unsigned j = (unsigned)i - r * 29u;
                int c = (e == 0) ? v.x : (e == 1) ? v.y : (e == 2) ? v.z : v.w;
                ushort h = tabh[j * 8 + c];
                *(ushort*)(s_x + r * XSTRIDE + 14 + 2 * j) = h;
            }
        }
    }
    __syncthreads();

    const int rb = w * 64;  // this wave's row strip
    const ushort* w1p = (const ushort*)(ws + W1_B);
    const ushort* w2p = (const ushort*)(ws + W2_B);
    const ushort* w3p = (const ushort*)(ws + W3_B);
    const float* b1p = (const float*)(ws + B1_B);
    const float* b2p = (const float*)(ws + B2_B);
    const float* b3p = (const float*)(ws + B3_B);
    const float* w4p = (const float*)(ws + W4_B);
    const float* b4p = (const float*)(ws + B4_B);

    // ---- weight A-fragments (features = m), held across tiles ----
    f16x8 a1[3][2], a2[2][2], a3;
#pragma unroll
    for (int mt = 0; mt < 3; mt++) {
        a1[mt][0] = ldw_frag(w1p, mt * 16 + l15, 64, 0, g);
        a1[mt][1] = ldw_frag(w1p, mt * 16 + l15, 64, 32, g);
    }
#pragma unroll
    for (int mt = 0; mt < 2; mt++) {
        a2[mt][0] = ldw_frag(w2p, mt * 16 + l15, 64, 0, g);
        a2[mt][1] = ldw_frag(w2p, mt * 16 + l15, 64, 32, g);
    }
    a3 = ldw_frag(w3p, l15, 32, 0, g);

    // biases / fc4 (per-lane float4 at row m = mt*16 + 4g + r)
    const float4 b1v0 = *(const float4*)(b1p + 4 * g);
    const float4 b1v1 = *(const float4*)(b1p + 16 + 4 * g);
    const float4 b1v2 = *(const float4*)(b1p + 32 + 4 * g);
    const float4 b2v0 = *(const float4*)(b2p + 4 * g);
    const float4 b2v1 = *(const float4*)(b2p + 16 + 4 * g);
    const float4 b3v  = *(const float4*)(b3p + 4 * g);
    const float4 w4v  = *(const float4*)(w4p + 4 * g);
    const float b4s = *b4p;

    // ---- 4 batch tiles of 16 rows; whole chain in registers ----
#pragma unroll
    for (int bt = 0; bt < 4; bt++) {
        const char* xr = s_x + (rb + 16 * bt + l15) * XSTRIDE;
        uint2 q0 = *(const uint2*)(xr + 8 * g);        // features 4g..4g+3
        uint2 q1 = *(const uint2*)(xr + 32 + 8 * g);   // features 16+4g..19+4g
        uint2 q2 = *(const uint2*)(xr + 64);           // features 32..35
        f16x8 xb0 = mk8(q0.x, q0.y, q1.x, q1.y);
        f16x8 xb1 = mk8(g == 0 ? q2.x : 0u, g == 0 ? q2.y : 0u, 0u, 0u);

        // fc1: h1^T tiles (features 0..47)
        f32x4 c10 = f32x4{b1v0.x, b1v0.y, b1v0.z, b1v0.w};
        f32x4 c11 = f32x4{b1v1.x, b1v1.y, b1v1.z, b1v1.w};
        f32x4 c12 = f32x4{b1v2.x, b1v2.y, b1v2.z, b1v2.w};
        c10 = __builtin_amdgcn_mfma_f32_16x16x32_f16(a1[0][0], xb0, c10, 0, 0, 0);
        c11 = __builtin_amdgcn_mfma_f32_16x16x32_f16(a1[1][0], xb0, c11, 0, 0, 0);
        c12 = __builtin_amdgcn_mfma_f32_16x16x32_f16(a1[2][0], xb0, c12, 0, 0, 0);
        c10 = __builtin_amdgcn_mfma_f32_16x16x32_f16(a1[0][1], xb1, c10, 0, 0, 0);
        c11 = __builtin_amdgcn_mfma_f32_16x16x32_f16(a1[1][1], xb1, c11, 0, 0, 0);
        c12 = __builtin_amdgcn_mfma_f32_16x16x32_f16(a1[2][1], xb1, c12, 0, 0, 0);

        // relu + pack: C1 tiles are exactly fc2's B-fragments
        f16x8 h0 = mk8(pkrelu(c10.x, c10.y), pkrelu(c10.z, c10.w),
                       pkrelu(c11.x, c11.y), pkrelu(c11.z, c11.w));
        f16x8 h1 = mk8(pkrelu(c12.x, c12.y), pkrelu(c12.z, c12.w), 0u, 0u);

        // fc2
        f32x4 c20 = f32x4{b2v0.x, b2v0.y, b2v0.z, b2v0.w};
        f32x4 c21 = f32x4{b2v1.x, b2v1.y, b2v1.z, b2v1.w};
        c20 = __builtin_amdgcn_mfma_f32_16x16x32_f16(a2[0][0], h0, c20, 0, 0, 0);
        c21 = __builtin_amdgcn_mfma_f32_16x16x32_f16(a2[1][0], h0, c21, 0, 0, 0);
        c20 = __builtin_amdgcn_mfma_f32_16x16x32_f16(a2[0][1], h1, c20, 0, 0, 0);
        c21 = __builtin_amdgcn_mfma_f32_16x16x32_f16(a2[1][1], h1, c21, 0, 0, 0);

        // fc3
        f16x8 h2 = mk8(pkrelu(c20.x, c20.y), pkrelu(c20.z, c20.w),
                       pkrelu(c21.x, c21.y), pkrelu(c21.z, c21.w));
        f32x4 c3 = f32x4{b3v.x, b3v.y, b3v.z, b3v.w};
        c3 = __builtin_amdgcn_mfma_f32_16x16x32_f16(a3, h2, c3, 0, 0, 0);

        // fc4 delta + sigmoid: reduce feature partials across g-groups
        float part = fmaxf(c3.x, 0.f) * w4v.x + fmaxf(c3.y, 0.f) * w4v.y +
                     fmaxf(c3.z, 0.f) * w4v.z + fmaxf(c3.w, 0.f) * w4v.w;
        part += __shfl_xor(part, 16);
        part += __shfl_xor(part, 32);
        float d = part + b4s;
        float p1 = 1.f / (1.f + __expf(-d));
        if (g == 0)
            out[blockIdx.x * 256 + rb + 16 * bt + l15] = make_float2(1.f - p1, p1);
    }
}

extern "C" void kernel_launch(void* const* d_in, const int* in_sizes, int n_in,
                              void* d_out, int out_size, void* d_ws, size_t ws_size,
                              hipStream_t stream) {
    (void)in_sizes; (void)n_in; (void)ws_size; (void)out_size;
    char* ws = (char*)d_ws;
    prep_kernel<<<1, NTHR, 0, stream>>>(
        (const float*)d_in[2],  (const float*)d_in[3],
        (const float*)d_in[4],  (const float*)d_in[5],
        (const float*)d_in[6],
        (const float*)d_in[7],  (const float*)d_in[8],
        (const float*)d_in[9],  (const float*)d_in[10],
        (const float*)d_in[11], (const float*)d_in[12],
        (const float*)d_in[13], (const float*)d_in[14],
        (const float*)d_in[15], (const float*)d_in[16],
        (const float*)d_in[17], (const float*)d_in[18],
        (const float*)d_in[19], (const float*)d_in[20],
        (const float*)d_in[21], (const float*)d_in[22],
        (const float*)d_in[23], (const float*)d_in[24],
        (const float*)d_in[25], (const float*)d_in[26],
        (const float*)d_in[27], (const float*)d_in[28],
        (const float*)d_in[29], (const float*)d_in[30],
        ws);
    recovery_net_kernel<<<NBLOCKS, NTHR, 0, stream>>>(
        (const float*)d_in[0], (const int*)d_in[1], ws, (float2*)d_out);
}